// Round 1
// baseline (6315.269 us; speedup 1.0000x reference)
//
#include <hip/hip_runtime.h>
#include <math.h>

// Problem constants: B=2, S=4096, H=2048, 8 heads x 256, 1 KV head.
constexpr float QSCALE = 0.0625f; // 1/sqrt(256), folded into q during RoPE

// ---------------------------------------------------------------------------
// Generic tiled f32 GEMM: C = A(MxK) @ B(KxN)   (B optionally transposed: NxK)
// BM=BN=128, BK=8, 256 threads, 8x8 microtile per thread.
// TRANSB: B matrix is stored N x K row-major (used for Q@K^T).
// QOUT:   write C in the (b,h,s,d) q-layout instead of row-major.
// CAUSAL: 0 none; 1 scores (skip tiles above diagonal); 2 PV (clip K extent).
// Per-z pointer offsets: off = (z/div)*s1 + (z%div)*s0 for each of A,B,C.
// ---------------------------------------------------------------------------
template<int TRANSB, int QOUT, int CAUSAL>
__global__ __launch_bounds__(256)
void sgemm(const float* __restrict__ Abase, const float* __restrict__ Bbase,
           float* __restrict__ Cbase,
           int M, int N, int K, int ldc,
           long sA1, long sA0, int divA,
           long sB1, long sB0, int divB,
           long sC1, long sC0, int divC)
{
    const int z = blockIdx.z;
    const float* A  = Abase + (z / divA) * sA1 + (z % divA) * sA0;
    const float* Bm = Bbase + (z / divB) * sB1 + (z % divB) * sB0;
    float*       C  = Cbase + (z / divC) * sC1 + (z % divC) * sC0;

    const int jt = blockIdx.x;
    const int it = CAUSAL ? (gridDim.y - 1 - blockIdx.y) : blockIdx.y; // big tiles first
    if (CAUSAL == 1 && jt > it) return;  // block-uniform exit, fully above diagonal
    const int bm = it * 128, bn = jt * 128;
    const int Klim = (CAUSAL == 2) ? (((it + 1) * 128 < K) ? (it + 1) * 128 : K) : K;

    __shared__ float As[8][132];   // [k][m], padded: transpose-store conflict-free
    __shared__ float Bs[8][132];   // [k][n]

    const int tid = threadIdx.x;
    const int tx = tid & 15, ty = tid >> 4;

    float acc[8][8];
#pragma unroll
    for (int i = 0; i < 8; ++i)
#pragma unroll
        for (int j = 0; j < 8; ++j) acc[i][j] = 0.f;

    const int arow = tid >> 1;          // 0..127
    const int acol = (tid & 1) << 2;    // 0 or 4
    const int br = tid >> 5;            // 0..7   (!TRANSB B-load)
    const int bc = (tid & 31) << 2;     // 0..124

    for (int k0 = 0; k0 < Klim; k0 += 8) {
        float4 av = *(const float4*)(A + (long)(bm + arow) * K + k0 + acol);
        float4 bv;
        if (!TRANSB) {
            bv = *(const float4*)(Bm + (long)(k0 + br) * N + bn + bc);
        } else {
            bv = *(const float4*)(Bm + (long)(bn + arow) * K + k0 + acol);
        }
        __syncthreads();   // previous iteration's LDS reads complete
        As[acol + 0][arow] = av.x;
        As[acol + 1][arow] = av.y;
        As[acol + 2][arow] = av.z;
        As[acol + 3][arow] = av.w;
        if (!TRANSB) {
            *(float4*)&Bs[br][bc] = bv;
        } else {
            Bs[acol + 0][arow] = bv.x;
            Bs[acol + 1][arow] = bv.y;
            Bs[acol + 2][arow] = bv.z;
            Bs[acol + 3][arow] = bv.w;
        }
        __syncthreads();
#pragma unroll
        for (int kk = 0; kk < 8; ++kk) {
            float a[8], b[8];
            *(float4*)&a[0] = *(const float4*)&As[kk][ty * 8];
            *(float4*)&a[4] = *(const float4*)&As[kk][ty * 8 + 4];
            *(float4*)&b[0] = *(const float4*)&Bs[kk][tx * 8];
            *(float4*)&b[4] = *(const float4*)&Bs[kk][tx * 8 + 4];
#pragma unroll
            for (int i = 0; i < 8; ++i)
#pragma unroll
                for (int j = 0; j < 8; ++j)
                    acc[i][j] = fmaf(a[i], b[j], acc[i][j]);
        }
    }

#pragma unroll
    for (int mi = 0; mi < 8; ++mi) {
        const int row = bm + ty * 8 + mi;
#pragma unroll
        for (int nc = 0; nc < 2; ++nc) {
            const int col = bn + tx * 8 + nc * 4;
            float4 v = make_float4(acc[mi][nc * 4 + 0], acc[mi][nc * 4 + 1],
                                   acc[mi][nc * 4 + 2], acc[mi][nc * 4 + 3]);
            long idx;
            if (QOUT) {
                const int b_ = row >> 12, s_ = row & 4095;
                const int h = col >> 8, d = col & 255;
                idx = ((long)(b_ * 8 + h) * 4096 + s_) * 256 + d;
            } else {
                idx = (long)row * ldc + col;
            }
            *(float4*)(C + idx) = v;
        }
    }
}

// ---------------------------------------------------------------------------
// RoPE (in-place on q and k), also folds the 1/sqrt(D) score scale into q.
// One block per (b,s); j = rotation-pair index 0..127.
// ---------------------------------------------------------------------------
__global__ __launch_bounds__(256)
void rope_kernel(float* __restrict__ q, float* __restrict__ k,
                 const int* __restrict__ pos_ids)
{
    const int blk = blockIdx.x;          // b*4096 + s
    const int t = threadIdx.x;
    const int j = t & 127;
    const float pos = (float)pos_ids[blk];
    const float invf = powf(10000.0f, -(float)j * (1.0f / 128.0f));
    float sn, cs;
    sincosf(pos * invf, &sn, &cs);

    if (t < 128) {                        // k: one kv head
        float* kp = k + (long)blk * 256;
        const float x1 = kp[j], x2 = kp[j + 128];
        kp[j]       = x1 * cs - x2 * sn;
        kp[j + 128] = x2 * cs + x1 * sn;
    }
    const int b_ = blk >> 12, s_ = blk & 4095;
    for (int h = (t >> 7); h < 8; h += 2) {   // 2 thread-groups x 4 heads
        float* qp = q + ((long)(b_ * 8 + h) * 4096 + s_) * 256;
        const float x1 = qp[j], x2 = qp[j + 128];
        qp[j]       = (x1 * cs - x2 * sn) * QSCALE;
        qp[j + 128] = (x2 * cs + x1 * sn) * QSCALE;
    }
}

// ---------------------------------------------------------------------------
// Row softmax over raw scores in the attn buffer (in-place), causal:
// valid columns j<=i get exp(s-m)/l, columns j>i get exact 0.0.
// One 256-thread block per (bh, row).
// ---------------------------------------------------------------------------
__global__ __launch_bounds__(256)
void softmax_kernel(float* __restrict__ attn)
{
    const long i = blockIdx.x;
    const long bh = blockIdx.y;
    float* row = attn + (bh * 4096 + i) * 4096;
    const int tid = threadIdx.x;
    const int n = (int)i + 1;
    __shared__ float red[8];

    float m = -3.0e38f;
    for (int jj = tid; jj < n; jj += 256) m = fmaxf(m, row[jj]);
#pragma unroll
    for (int off = 32; off; off >>= 1) m = fmaxf(m, __shfl_xor(m, off));
    if ((tid & 63) == 0) red[tid >> 6] = m;
    __syncthreads();
    m = fmaxf(fmaxf(red[0], red[1]), fmaxf(red[2], red[3]));

    float l = 0.f;
    for (int jj = tid; jj < n; jj += 256) l += __expf(row[jj] - m);
#pragma unroll
    for (int off = 32; off; off >>= 1) l += __shfl_xor(l, off);
    if ((tid & 63) == 0) red[4 + (tid >> 6)] = l;
    __syncthreads();
    l = (red[4] + red[5]) + (red[6] + red[7]);
    const float rl = 1.0f / l;

    for (int jj = tid; jj < n; jj += 256) row[jj] = __expf(row[jj] - m) * rl;
    for (int jj = n + tid; jj < 4096; jj += 256) row[jj] = 0.f;
}

// ---------------------------------------------------------------------------
extern "C" void kernel_launch(void* const* d_in, const int* in_sizes, int n_in,
                              void* d_out, int out_size, void* d_ws, size_t ws_size,
                              hipStream_t stream)
{
    (void)in_sizes; (void)n_in; (void)out_size; (void)ws_size;
    const float* hidden = (const float*)d_in[0];
    // d_in[1] = attention_mask: structurally causal (0 / -1e9) -> not read.
    const int*   pos = (const int*)d_in[2];
    const float* Wq = (const float*)d_in[3];
    const float* Wk = (const float*)d_in[4];
    const float* Wv = (const float*)d_in[5];
    const float* Wo = (const float*)d_in[6];

    float* out  = (float*)d_out;            // attn_output: 16,777,216 f32
    float* attn = out + 16777216;           // attn probs: 268,435,456 f32

    float* q  = (float*)d_ws;               // (b,h,s,d)  64 MB
    float* kb = q + 16777216;               // (b,s,d)     8 MB
    float* vb = kb + 2097152;               // (b,s,d)     8 MB
    float* ao = vb + 2097152;               // (b,s,h*d)  64 MB

    // 1-3: projections. Q goes straight to (b,h,s,d) layout.
    sgemm<0,1,0><<<dim3(16, 64, 1), 256, 0, stream>>>(hidden, Wq, q,
        8192, 2048, 2048, 0,  0,0,1, 0,0,1, 0,0,1);
    sgemm<0,0,0><<<dim3(2, 64, 1), 256, 0, stream>>>(hidden, Wk, kb,
        8192, 256, 2048, 256, 0,0,1, 0,0,1, 0,0,1);
    sgemm<0,0,0><<<dim3(2, 64, 1), 256, 0, stream>>>(hidden, Wv, vb,
        8192, 256, 2048, 256, 0,0,1, 0,0,1, 0,0,1);

    // 4: RoPE (+ q *= 1/16)
    rope_kernel<<<dim3(8192, 1, 1), 256, 0, stream>>>(q, kb, pos);

    // 5: raw scores into attn buffer; z = b*8+h; causal tiles only.
    sgemm<1,0,1><<<dim3(32, 32, 16), 256, 0, stream>>>(q, kb, attn,
        4096, 4096, 256, 4096,
        1048576,0,1,   1048576,0,8,   16777216,0,1);

    // 6: softmax rows (writes probs + explicit causal zeros -> whole attn output)
    softmax_kernel<<<dim3(4096, 16, 1), 256, 0, stream>>>(attn);

    // 7: PV; K extent clipped to causal region; ao layout (b,s,h*256+d).
    sgemm<0,0,2><<<dim3(2, 32, 16), 256, 0, stream>>>(attn, vb, ao,
        4096, 256, 4096, 2048,
        16777216,0,1,  1048576,0,8,  8388608,256,8);

    // 8: attn_output = ao @ Wo
    sgemm<0,0,0><<<dim3(16, 64, 1), 256, 0, stream>>>(ao, Wo, out,
        8192, 2048, 2048, 2048, 0,0,1, 0,0,1, 0,0,1);
}

// Round 11
// 2208.821 us; speedup vs baseline: 2.8591x; 2.8591x over previous
//
#include <hip/hip_runtime.h>
#include <math.h>
#include <stdint.h>

// B=2, S=4096, H=2048, 8 heads x 256, 1 KV head. All GEMMs via bf16 MFMA.

typedef __attribute__((ext_vector_type(8))) short bf16x8;  // 4 VGPR = 8 bf16
typedef __attribute__((ext_vector_type(4))) float f32x4;   // MFMA accumulator

__device__ __forceinline__ unsigned short f2bf(float x) {  // RNE f32->bf16
    union { float f; unsigned u; } v; v.f = x;
    unsigned r = v.u + 0x7FFFu + ((v.u >> 16) & 1u);
    return (unsigned short)(r >> 16);
}

__device__ __forceinline__ void gload_lds16(const void* gp, void* lp) {
    __builtin_amdgcn_global_load_lds(
        (const __attribute__((address_space(1))) unsigned int*)gp,
        (__attribute__((address_space(3))) unsigned int*)lp, 16, 0, 0);
}

// ---------------------------------------------------------------------------
// BT-GEMM: C = A(MxK) @ B(NxK)^T, bf16 MFMA 16x16x32, f32 accumulate.
// 128x128 tile, BK=64, 256 threads = 4 waves in 2x2, wave tile 64x64.
// AF32:  A is f32 in global; reg-stage + convert + ds_write (PV path).
//        else A is bf16; global_load_lds direct (linear LDS, m97 style).
// COUT:  0 f32 row-major(ldc); 1 q-layout f32 (b,h,s,d); 2 v_t bf16 (b,d,s);
//        3 bf16 row-major(ldc).
// CAUSAL:0 none; 1 skip tiles jt>it (scores); 2 clip K to (it+1)*128 (PV).
// Per-z operand offset: off = (z/div)*s1 + (z%div)*s0  (element units).
// ---------------------------------------------------------------------------
template<int AF32, int COUT, int CAUSAL>
__global__ __launch_bounds__(256)
void bgemm(const void* __restrict__ Abase, const unsigned short* __restrict__ Bbase,
           void* __restrict__ Cbase, int M, int N, int K, int ldc,
           long sA1, long sA0, int divA,
           long sB1, long sB0, int divB,
           long sC1, long sC0, int divC)
{
    const int z  = blockIdx.z;
    const int jt = blockIdx.x;
    const int it = CAUSAL ? (int)(gridDim.y - 1 - blockIdx.y) : (int)blockIdx.y;
    if (CAUSAL == 1 && jt > it) return;           // fully above diagonal
    const int bm = it * 128, bn = jt * 128;
    const int Klim = (CAUSAL == 2) ? (((it + 1) * 128 < K) ? (it + 1) * 128 : K) : K;

    __shared__ unsigned short As[8192];           // 128 x 64 bf16, row-major, linear
    __shared__ unsigned short Bs[8192];

    const int t = threadIdx.x;
    const int lane = t & 63, wv = t >> 6;
    const int wr = wv >> 1, wc = wv & 1;          // wave 2x2 grid
    const int srow = t >> 3;                      // staging row 0..31 (+32*i)
    const int scol = (t & 7) << 3;                // staging col (elements)
    const int fr = lane & 15;                     // fragment row/col within 16
    const int fk = (lane >> 4) << 3;              // fragment k-offset within 32

    const unsigned short* Ab  = (const unsigned short*)Abase + (z / divA) * sA1 + (z % divA) * sA0;
    const float*          Afp = (const float*)Abase          + (z / divA) * sA1 + (z % divA) * sA0;
    const unsigned short* Bb  = Bbase + (z / divB) * sB1 + (z % divB) * sB0;

    f32x4 acc[4][4];
#pragma unroll
    for (int mi = 0; mi < 4; ++mi)
#pragma unroll
        for (int nj = 0; nj < 4; ++nj) acc[mi][nj] = (f32x4){0.f, 0.f, 0.f, 0.f};

    for (int k0 = 0; k0 < Klim; k0 += 64) {
        __syncthreads();                          // previous tile's LDS reads done
        if constexpr (!AF32) {
#pragma unroll
            for (int i = 0; i < 4; ++i)           // A: 128x64 bf16, dst linear = t*16B + i*4KB
                gload_lds16(Ab + (long)(bm + srow + 32 * i) * K + k0 + scol,
                            &As[wv * 512 + i * 2048]);
        } else {
#pragma unroll
            for (int i = 0; i < 4; ++i) {         // A f32 -> bf16 reg-stage
                const float* p = Afp + (long)(bm + srow + 32 * i) * K + k0 + scol;
                float4 x0 = *(const float4*)p;
                float4 x1 = *(const float4*)(p + 4);
                union { bf16x8 v; unsigned short u[8]; } pk;
                pk.u[0] = f2bf(x0.x); pk.u[1] = f2bf(x0.y);
                pk.u[2] = f2bf(x0.z); pk.u[3] = f2bf(x0.w);
                pk.u[4] = f2bf(x1.x); pk.u[5] = f2bf(x1.y);
                pk.u[6] = f2bf(x1.z); pk.u[7] = f2bf(x1.w);
                *(bf16x8*)&As[(srow + 32 * i) * 64 + scol] = pk.v;
            }
        }
#pragma unroll
        for (int i = 0; i < 4; ++i)               // B tile (N x K form): same pattern
            gload_lds16(Bb + (long)(bn + srow + 32 * i) * K + k0 + scol,
                        &Bs[wv * 512 + i * 2048]);
        __syncthreads();                          // staging visible (vmcnt+lgkm drain)

#pragma unroll
        for (int kk = 0; kk < 64; kk += 32) {
            bf16x8 af[4], bfv[4];
#pragma unroll
            for (int mi = 0; mi < 4; ++mi)
                af[mi] = *(const bf16x8*)&As[(wr * 64 + mi * 16 + fr) * 64 + kk + fk];
#pragma unroll
            for (int nj = 0; nj < 4; ++nj)
                bfv[nj] = *(const bf16x8*)&Bs[(wc * 64 + nj * 16 + fr) * 64 + kk + fk];
#pragma unroll
            for (int mi = 0; mi < 4; ++mi)
#pragma unroll
                for (int nj = 0; nj < 4; ++nj)
                    acc[mi][nj] = __builtin_amdgcn_mfma_f32_16x16x32_bf16(
                        af[mi], bfv[nj], acc[mi][nj], 0, 0, 0);
        }
    }

    // Epilogue. C/D layout: col = lane&15, row = (lane>>4)*4 + reg  [m89-verified]
    float*          Cf = (float*)Cbase          + (z / divC) * sC1 + (z % divC) * sC0;
    unsigned short* Cu = (unsigned short*)Cbase + (z / divC) * sC1 + (z % divC) * sC0;
    const int r0 = (lane >> 4) << 2;
    const int c0 = lane & 15;
#pragma unroll
    for (int mi = 0; mi < 4; ++mi) {
#pragma unroll
        for (int nj = 0; nj < 4; ++nj) {
            const int col = bn + wc * 64 + nj * 16 + c0;
#pragma unroll
            for (int j = 0; j < 4; ++j) {
                const int row = bm + wr * 64 + mi * 16 + r0 + j;
                const float vv = acc[mi][nj][j];
                if constexpr (COUT == 0) {
                    Cf[(long)row * ldc + col] = vv;
                } else if constexpr (COUT == 1) {      // q (b,h,s,d)
                    const int b_ = row >> 12, s_ = row & 4095;
                    const int h = col >> 8, d = col & 255;
                    Cf[((long)(b_ * 8 + h) * 4096 + s_) * 256 + d] = vv;
                } else if constexpr (COUT == 2) {      // v_t (b,d,s) bf16
                    const int b_ = row >> 12, s_ = row & 4095;
                    Cu[(long)(b_ * 256 + col) * 4096 + s_] = f2bf(vv);
                } else {                               // bf16 row-major
                    Cu[(long)row * ldc + col] = f2bf(vv);
                }
            }
        }
    }
}

// ---------------------------------------------------------------------------
// f32 -> bf16 elementwise cast (vectorized), grid-stride.
// ---------------------------------------------------------------------------
__global__ __launch_bounds__(256)
void castbf(const float* __restrict__ in, unsigned short* __restrict__ out, long n)
{
    long i = ((long)blockIdx.x * 256 + threadIdx.x) * 4;
    const long stride = (long)gridDim.x * 1024;
    for (; i < n; i += stride) {
        float4 x = *(const float4*)(in + i);
        union { unsigned long long ll; unsigned short u[4]; } o;
        o.u[0] = f2bf(x.x); o.u[1] = f2bf(x.y); o.u[2] = f2bf(x.z); o.u[3] = f2bf(x.w);
        *(unsigned long long*)(out + i) = o.ll;
    }
}

// ---------------------------------------------------------------------------
// Transpose + cast: in (R x C f32, row-major) -> out (C x R bf16, row-major).
// 64x64 LDS tile, both sides coalesced, conflict-free readback.
// ---------------------------------------------------------------------------
__global__ __launch_bounds__(256)
void tcast(const float* __restrict__ in, unsigned short* __restrict__ out, int R, int C)
{
    __shared__ float ts[64][65];
    const int t = threadIdx.x;
    const int c0 = blockIdx.x * 64, r0 = blockIdx.y * 64;
    const int cc = t & 63, rr = t >> 6;
#pragma unroll
    for (int i = 0; i < 16; ++i)
        ts[rr + 4 * i][cc] = in[(long)(r0 + rr + 4 * i) * C + c0 + cc];
    __syncthreads();
#pragma unroll
    for (int i = 0; i < 16; ++i)
        out[(long)(c0 + rr + 4 * i) * R + r0 + cc] = f2bf(ts[cc][rr + 4 * i]);
}

// ---------------------------------------------------------------------------
// RoPE: read f32 q (b,h,s,d) / k (b,s,d), write bf16 copies; folds 1/16 into q.
// ---------------------------------------------------------------------------
__global__ __launch_bounds__(256)
void rope_kernel(const float* __restrict__ qf, const float* __restrict__ kf,
                 unsigned short* __restrict__ qb, unsigned short* __restrict__ kb,
                 const int* __restrict__ pos_ids)
{
    const int blk = blockIdx.x;          // b*4096 + s
    const int t = threadIdx.x;
    const int j = t & 127;
    const float pos = (float)pos_ids[blk];
    const float invf = powf(10000.0f, -(float)j * (1.0f / 128.0f));
    float sn, cs;
    sincosf(pos * invf, &sn, &cs);

    if (t < 128) {
        const float* kp = kf + (long)blk * 256;
        unsigned short* ko = kb + (long)blk * 256;
        const float x1 = kp[j], x2 = kp[j + 128];
        ko[j]       = f2bf(x1 * cs - x2 * sn);
        ko[j + 128] = f2bf(x2 * cs + x1 * sn);
    }
    const int b_ = blk >> 12, s_ = blk & 4095;
    for (int h = (t >> 7); h < 8; h += 2) {
        const long base = ((long)(b_ * 8 + h) * 4096 + s_) * 256;
        const float x1 = qf[base + j], x2 = qf[base + j + 128];
        qb[base + j]       = f2bf((x1 * cs - x2 * sn) * 0.0625f);
        qb[base + j + 128] = f2bf((x2 * cs + x1 * sn) * 0.0625f);
    }
}

// ---------------------------------------------------------------------------
// Row softmax, causal, in-place on f32 scores. Row held in registers: one
// global read + one write. Block 256 threads per (row, bh).
// ---------------------------------------------------------------------------
__global__ __launch_bounds__(256)
void softmax_kernel(float* __restrict__ attn)
{
    const long i = blockIdx.x, bh = blockIdx.y;
    float* row = attn + (bh * 4096 + i) * 4096;
    const int tid = threadIdx.x;
    const int n = (int)i + 1;
    __shared__ float red[8];
    float va[16];

    float m = -3.0e38f;
#pragma unroll
    for (int c = 0; c < 16; ++c) {
        va[c] = -3.0e38f;
        if (c * 256 < n) {                 // block-uniform
            const int jj = c * 256 + tid;
            if (jj < n) va[c] = row[jj];
        }
        m = fmaxf(m, va[c]);
    }
#pragma unroll
    for (int off = 32; off; off >>= 1) m = fmaxf(m, __shfl_xor(m, off));
    if ((tid & 63) == 0) red[tid >> 6] = m;
    __syncthreads();
    m = fmaxf(fmaxf(red[0], red[1]), fmaxf(red[2], red[3]));

    float l = 0.f;
#pragma unroll
    for (int c = 0; c < 16; ++c) {
        va[c] = __expf(va[c] - m);         // masked slots: exp(-3e38-m) == 0
        l += va[c];
    }
#pragma unroll
    for (int off = 32; off; off >>= 1) l += __shfl_xor(l, off);
    if ((tid & 63) == 0) red[4 + (tid >> 6)] = l;
    __syncthreads();
    l = (red[4] + red[5]) + (red[6] + red[7]);
    const float rl = 1.0f / l;

#pragma unroll
    for (int c = 0; c < 16; ++c) {
        if (c * 256 < n) {
            const int jj = c * 256 + tid;
            if (jj < n) row[jj] = va[c] * rl;
        }
    }
    for (int jj = n + tid; jj < 4096; jj += 256) row[jj] = 0.f;
}

// ---------------------------------------------------------------------------
extern "C" void kernel_launch(void* const* d_in, const int* in_sizes, int n_in,
                              void* d_out, int out_size, void* d_ws, size_t ws_size,
                              hipStream_t stream)
{
    (void)in_sizes; (void)n_in; (void)out_size; (void)ws_size;
    const float* hidden = (const float*)d_in[0];
    // d_in[1] attention_mask: structurally causal -> not read.
    const int*   pos = (const int*)d_in[2];
    const float* Wq = (const float*)d_in[3];
    const float* Wk = (const float*)d_in[4];
    const float* Wv = (const float*)d_in[5];
    const float* Wo = (const float*)d_in[6];

    float* out  = (float*)d_out;                 // 16,777,216 f32
    float* attn = out + 16777216;                // 268,435,456 f32

    // Workspace layout (130 MB; <=151 MB proven available in Round 1)
    unsigned short* hid_bf = (unsigned short*)d_ws;        // 32MB
    unsigned short* WqT = hid_bf + 16777216;               //  8MB (2048x2048 NxK)
    unsigned short* WkT = WqT + 4194304;                   //  1MB (256x2048)
    unsigned short* WvT = WkT + 524288;                    //  1MB (256x2048)
    unsigned short* WoT = WvT + 524288;                    //  8MB (2048x2048)
    float* q_f32 = (float*)(WoT + 4194304);                // 64MB (b,h,s,d)
    float* k_f32 = q_f32 + 16777216;                       //  8MB (b,s,d)
    unsigned short* v_t  = (unsigned short*)(k_f32 + 2097152); // 4MB (b,d,s) bf16
    unsigned short* k_bf = v_t + 2097152;                  //  4MB (b,s,d) bf16
    unsigned short* q_bf = hid_bf;     // overlay: hidden dead after V-proj
    unsigned short* ao   = (unsigned short*)q_f32; // overlay: q_f32 dead after rope

    // Casts
    castbf<<<dim3(2048), 256, 0, stream>>>(hidden, hid_bf, 16777216L);
    tcast<<<dim3(32, 32), 256, 0, stream>>>(Wq, WqT, 2048, 2048);
    tcast<<<dim3(4, 32), 256, 0, stream>>>(Wk, WkT, 2048, 256);
    tcast<<<dim3(4, 32), 256, 0, stream>>>(Wv, WvT, 2048, 256);
    tcast<<<dim3(32, 32), 256, 0, stream>>>(Wo, WoT, 2048, 2048);

    // Projections
    bgemm<0,1,0><<<dim3(16, 64, 1), 256, 0, stream>>>(hid_bf, WqT, q_f32,
        8192, 2048, 2048, 0,      0,0,1, 0,0,1, 0,0,1);
    bgemm<0,0,0><<<dim3(2, 64, 1), 256, 0, stream>>>(hid_bf, WkT, k_f32,
        8192, 256, 2048, 256,     0,0,1, 0,0,1, 0,0,1);
    bgemm<0,2,0><<<dim3(2, 64, 1), 256, 0, stream>>>(hid_bf, WvT, v_t,
        8192, 256, 2048, 0,       0,0,1, 0,0,1, 0,0,1);

    // RoPE -> bf16 q,k (q scaled by 1/16)
    rope_kernel<<<dim3(8192), 256, 0, stream>>>(q_f32, k_f32, q_bf, k_bf, pos);

    // Scores (causal tiles only) -> attn f32
    bgemm<0,0,1><<<dim3(32, 32, 16), 256, 0, stream>>>(q_bf, k_bf, attn,
        4096, 4096, 256, 4096,    1048576,0,1, 1048576,0,8, 16777216,0,1);

    // Softmax (writes probs + causal zeros = full attn output)
    softmax_kernel<<<dim3(4096, 16), 256, 0, stream>>>(attn);

    // PV (A = probs f32 reg-staged to bf16; K clipped causal) -> ao bf16
    bgemm<1,3,2><<<dim3(2, 32, 16), 256, 0, stream>>>(attn, v_t, ao,
        4096, 256, 4096, 2048,    16777216,0,1, 1048576,0,8, 8388608,256,8);

    // O-projection
    bgemm<0,0,0><<<dim3(16, 64, 1), 256, 0, stream>>>(ao, WoT, out,
        8192, 2048, 2048, 2048,   0,0,1, 0,0,1, 0,0,1);
}